// Round 1
// baseline (516.669 us; speedup 1.0000x reference)
//
#include <hip/hip_runtime.h>
#include <stdint.h>

// FastAttention on MI355X (gfx950).
// Folded algebra:
//   q = x@Wq ; gq[b,d] = sum_n q*softmax_d(q*alpha*scale)
//   k = x@Wk ; p = gq*k ; gk[b,d] = sum_n p*softmax_d(p*beta*scale)
//   out[b] = x[b] @ (Wv @ diag(gk_b) @ Wr + Wq)     <- v / kv never materialized
// All GEMMs bf16 MFMA (16x16x32), fp32 accumulate.

#define NBATCH 8
#define SEQ 4096
#define KD 768               // DIM == DEC == 768
#define ROWS (NBATCH * SEQ)  // 32768

typedef __bf16 bf16x8 __attribute__((ext_vector_type(8)));
typedef float f32x4 __attribute__((ext_vector_type(4)));

__device__ __forceinline__ unsigned short f2bf(float f) {
    __bf16 h = (__bf16)f;
    return __builtin_bit_cast(unsigned short, h);
}

__device__ __forceinline__ void gload16(const void* g, void* l) {
    __builtin_amdgcn_global_load_lds((const __attribute__((address_space(1))) void*)g,
                                     (__attribute__((address_space(3))) void*)l, 16, 0, 0);
}

// ---------- conversions ----------

__global__ __launch_bounds__(256) void cvt_f32_bf16x8(const float* __restrict__ src,
                                                      unsigned short* __restrict__ dst, int n8) {
    int i = blockIdx.x * 256 + threadIdx.x;
    if (i >= n8) return;
    const float4* p = (const float4*)src + (size_t)i * 2;
    float4 a = p[0], b = p[1];
    union { unsigned short s[8]; uint4 u; } t;
    t.s[0] = f2bf(a.x); t.s[1] = f2bf(a.y); t.s[2] = f2bf(a.z); t.s[3] = f2bf(a.w);
    t.s[4] = f2bf(b.x); t.s[5] = f2bf(b.y); t.s[6] = f2bf(b.z); t.s[7] = f2bf(b.w);
    ((uint4*)dst)[i] = t.u;
}

// WT[n][k] = bf16(W[k][n]) — 32x32 LDS tile transpose, grid (24,24)
__global__ __launch_bounds__(256) void transpose_to_bf16(const float* __restrict__ W,
                                                         unsigned short* __restrict__ WT) {
    __shared__ float tile[32][33];
    int tx = threadIdx.x & 31, tg = threadIdx.x >> 5;  // tg in [0,8)
    int bi = blockIdx.x * 32, bj = blockIdx.y * 32;
#pragma unroll
    for (int j = 0; j < 4; ++j) {
        int r = tg * 4 + j;
        tile[r][tx] = W[(size_t)(bi + r) * KD + bj + tx];
    }
    __syncthreads();
#pragma unroll
    for (int j = 0; j < 4; ++j) {
        int r = tg * 4 + j;  // output row within block = input col
        WT[(size_t)(bj + r) * KD + bi + tx] = f2bf(tile[tx][r]);
    }
}

// ---------- GEMM core: 128x128 tile, BK=32, 4 waves (2x2), 16x16x32 bf16 MFMA ----------
// A: [M][768] bf16 row-major. B: [N][768] bf16 row-major (i.e. B^T of math B).

__device__ __forceinline__ void gemm_tile_128(const unsigned short* __restrict__ A,
                                              const unsigned short* __restrict__ B,
                                              int m0, int n0, short* sA, short* sB,
                                              f32x4 acc[4][4]) {
    const int tid = threadIdx.x;
    const int lane = tid & 63;
    const int wr = (tid >> 7) & 1;
    const int wc = (tid >> 6) & 1;
    const f32x4 zero = {0.f, 0.f, 0.f, 0.f};
#pragma unroll
    for (int m = 0; m < 4; ++m)
#pragma unroll
        for (int n = 0; n < 4; ++n) acc[m][n] = zero;

    // staging: linear LDS bytes [t*16, t*16+16) and +4096; row = o>>6 (64B rows = 32 bf16)
    const int o1 = tid * 16, o2 = tid * 16 + 4096;
    const char* a1 = (const char*)A + (size_t)(m0 + (o1 >> 6)) * (KD * 2) + (o1 & 63);
    const char* a2 = (const char*)A + (size_t)(m0 + (o2 >> 6)) * (KD * 2) + (o2 & 63);
    const char* b1 = (const char*)B + (size_t)(n0 + (o1 >> 6)) * (KD * 2) + (o1 & 63);
    const char* b2 = (const char*)B + (size_t)(n0 + (o2 >> 6)) * (KD * 2) + (o2 & 63);
    char* lA1 = (char*)sA + o1; char* lA2 = (char*)sA + o2;
    char* lB1 = (char*)sB + o1; char* lB2 = (char*)sB + o2;

    const int kof = (lane >> 4) * 8;
    const short* ap[4]; const short* bp[4];
#pragma unroll
    for (int m = 0; m < 4; ++m) ap[m] = sA + (wr * 64 + m * 16 + (lane & 15)) * 32 + kof;
#pragma unroll
    for (int n = 0; n < 4; ++n) bp[n] = sB + (wc * 64 + n * 16 + (lane & 15)) * 32 + kof;

    for (int kt = 0; kt < KD * 2; kt += 64) {  // 24 iterations, kt = K byte offset
        __syncthreads();
        gload16(a1 + kt, lA1);
        gload16(a2 + kt, lA2);
        gload16(b1 + kt, lB1);
        gload16(b2 + kt, lB2);
        __syncthreads();
        bf16x8 af[4], bv[4];
#pragma unroll
        for (int m = 0; m < 4; ++m) af[m] = *(const bf16x8*)ap[m];
#pragma unroll
        for (int n = 0; n < 4; ++n) bv[n] = *(const bf16x8*)bp[n];
#pragma unroll
        for (int m = 0; m < 4; ++m)
#pragma unroll
            for (int n = 0; n < 4; ++n)
                acc[m][n] = __builtin_amdgcn_mfma_f32_16x16x32_bf16(af[m], bv[n], acc[m][n], 0, 0, 0);
    }
}

// C/D layout (m89): col = lane&15, row = (lane>>4)*4 + reg

__global__ __launch_bounds__(256) void gemm_bf16(const unsigned short* __restrict__ A,
                                                 const unsigned short* __restrict__ B,
                                                 unsigned short* __restrict__ C) {
    __shared__ short sA[128 * 32];
    __shared__ short sB[128 * 32];
    f32x4 acc[4][4];
    const int m0 = blockIdx.y * 128, n0 = blockIdx.x * 128;
    gemm_tile_128(A, B, m0, n0, sA, sB, acc);
    const int lane = threadIdx.x & 63;
    const int wr = (threadIdx.x >> 7) & 1, wc = (threadIdx.x >> 6) & 1;
    const int r0 = m0 + wr * 64 + ((lane >> 4) * 4);
    const int c0 = n0 + wc * 64 + (lane & 15);
#pragma unroll
    for (int m = 0; m < 4; ++m)
#pragma unroll
        for (int n = 0; n < 4; ++n)
#pragma unroll
            for (int r = 0; r < 4; ++r)
                C[(size_t)(r0 + m * 16 + r) * KD + (c0 + n * 16)] = f2bf(acc[m][n][r]);
}

// W3T_b[e][i] = bf16( sum_d WrS_b[e][d]*Wv[i][d] + Wq[i][e] ), grid (6,6,8)
__global__ __launch_bounds__(256) void gemm_w3(const unsigned short* __restrict__ WrS,
                                               const unsigned short* __restrict__ Wvb,
                                               const float* __restrict__ Wq,
                                               unsigned short* __restrict__ W3T) {
    __shared__ short sA[128 * 32];
    __shared__ short sB[128 * 32];
    f32x4 acc[4][4];
    const int b = blockIdx.z;
    const unsigned short* A = WrS + (size_t)b * (KD * KD);
    unsigned short* out = W3T + (size_t)b * (KD * KD);
    const int m0 = blockIdx.y * 128, n0 = blockIdx.x * 128;
    gemm_tile_128(A, Wvb, m0, n0, sA, sB, acc);
    const int lane = threadIdx.x & 63;
    const int wr = (threadIdx.x >> 7) & 1, wc = (threadIdx.x >> 6) & 1;
    const int r0 = m0 + wr * 64 + ((lane >> 4) * 4);
    const int c0 = n0 + wc * 64 + (lane & 15);
#pragma unroll
    for (int m = 0; m < 4; ++m)
#pragma unroll
        for (int n = 0; n < 4; ++n)
#pragma unroll
            for (int r = 0; r < 4; ++r) {
                int row = r0 + m * 16 + r, col = c0 + n * 16;
                out[(size_t)row * KD + col] = f2bf(acc[m][n][r] + Wq[(size_t)col * KD + row]);
            }
}

// out[row][e] = sum_i xb[row][i] * W3T_b[e][i], fp32 out, grid (6,256)
__global__ __launch_bounds__(256) void gemm_out_f32(const unsigned short* __restrict__ xb,
                                                    const unsigned short* __restrict__ W3T,
                                                    float* __restrict__ out) {
    __shared__ short sA[128 * 32];
    __shared__ short sB[128 * 32];
    f32x4 acc[4][4];
    const int m0 = blockIdx.y * 128, n0 = blockIdx.x * 128;
    const unsigned short* B = W3T + (size_t)(blockIdx.y >> 5) * (KD * KD);  // 32 m-tiles/batch
    gemm_tile_128(xb, B, m0, n0, sA, sB, acc);
    const int lane = threadIdx.x & 63;
    const int wr = (threadIdx.x >> 7) & 1, wc = (threadIdx.x >> 6) & 1;
    const int r0 = m0 + wr * 64 + ((lane >> 4) * 4);
    const int c0 = n0 + wc * 64 + (lane & 15);
#pragma unroll
    for (int m = 0; m < 4; ++m)
#pragma unroll
        for (int n = 0; n < 4; ++n)
#pragma unroll
            for (int r = 0; r < 4; ++r)
                out[(size_t)(r0 + m * 16 + r) * KD + (c0 + n * 16)] = acc[m][n][r];
}

// ---------- softmax-weighted reductions (1 wave per row group; lane owns 12 of 768 d) ----------
// lane d map: part1 d = lane*8+j (j<8) covers [0,512); part2 d = 512+lane*4+j (j<4)

#define SM_SCALE 0.03608439182435161f  // 768^-0.5

__device__ __forceinline__ void unpack12(const unsigned short* rowp, int lane, float* q) {
    uint4 u = *(const uint4*)(rowp + lane * 8);
    uint2 v = *(const uint2*)(rowp + 512 + lane * 4);
    q[0] = __uint_as_float(u.x << 16);  q[1] = __uint_as_float(u.x & 0xffff0000u);
    q[2] = __uint_as_float(u.y << 16);  q[3] = __uint_as_float(u.y & 0xffff0000u);
    q[4] = __uint_as_float(u.z << 16);  q[5] = __uint_as_float(u.z & 0xffff0000u);
    q[6] = __uint_as_float(u.w << 16);  q[7] = __uint_as_float(u.w & 0xffff0000u);
    q[8] = __uint_as_float(v.x << 16);  q[9] = __uint_as_float(v.x & 0xffff0000u);
    q[10] = __uint_as_float(v.y << 16); q[11] = __uint_as_float(v.y & 0xffff0000u);
}

__device__ __forceinline__ void load12f(const float* base, int lane, float* o) {
    const float4* p0 = (const float4*)(base + lane * 8);
    float4 x0 = p0[0], x1 = p0[1];
    float4 x2 = *(const float4*)(base + 512 + lane * 4);
    o[0] = x0.x; o[1] = x0.y; o[2] = x0.z; o[3] = x0.w;
    o[4] = x1.x; o[5] = x1.y; o[6] = x1.z; o[7] = x1.w;
    o[8] = x2.x; o[9] = x2.y; o[10] = x2.z; o[11] = x2.w;
}

// grid (32, NBATCH): block handles 128 rows (4 waves x 32 rows)
__global__ __launch_bounds__(256) void reduce_gq(const unsigned short* __restrict__ qb,
                                                 const float* __restrict__ alpha,
                                                 float* __restrict__ gq) {
    const int b = blockIdx.y;
    const int lane = threadIdx.x & 63, wave = threadIdx.x >> 6;
    float al[12];
    load12f(alpha, lane, al);
    float acc[12];
#pragma unroll
    for (int j = 0; j < 12; ++j) acc[j] = 0.f;
    const int row0 = b * SEQ + blockIdx.x * 128 + wave * 32;
    for (int rr = 0; rr < 32; ++rr) {
        const unsigned short* rowp = qb + (size_t)(row0 + rr) * KD;
        float q[12], t[12];
        unpack12(rowp, lane, q);
        float mx = -1e30f;
#pragma unroll
        for (int j = 0; j < 12; ++j) { t[j] = q[j] * al[j] * SM_SCALE; mx = fmaxf(mx, t[j]); }
#pragma unroll
        for (int s = 32; s > 0; s >>= 1) mx = fmaxf(mx, __shfl_xor(mx, s));
        float sum = 0.f, e[12];
#pragma unroll
        for (int j = 0; j < 12; ++j) { e[j] = __expf(t[j] - mx); sum += e[j]; }
#pragma unroll
        for (int s = 32; s > 0; s >>= 1) sum += __shfl_xor(sum, s);
        float inv = 1.f / sum;
#pragma unroll
        for (int j = 0; j < 12; ++j) acc[j] += q[j] * e[j] * inv;
    }
    float* g = gq + b * KD;
#pragma unroll
    for (int j = 0; j < 8; ++j) atomicAdd(&g[lane * 8 + j], acc[j]);
#pragma unroll
    for (int j = 0; j < 4; ++j) atomicAdd(&g[512 + lane * 4 + j], acc[8 + j]);
}

__global__ __launch_bounds__(256) void reduce_gk(const unsigned short* __restrict__ kb,
                                                 const float* __restrict__ gq,
                                                 const float* __restrict__ beta,
                                                 float* __restrict__ gk) {
    const int b = blockIdx.y;
    const int lane = threadIdx.x & 63, wave = threadIdx.x >> 6;
    float bt[12], gv[12];
    load12f(beta, lane, bt);
    load12f(gq + b * KD, lane, gv);
    float acc[12];
#pragma unroll
    for (int j = 0; j < 12; ++j) acc[j] = 0.f;
    const int row0 = b * SEQ + blockIdx.x * 128 + wave * 32;
    for (int rr = 0; rr < 32; ++rr) {
        const unsigned short* rowp = kb + (size_t)(row0 + rr) * KD;
        float k[12], p[12], t[12];
        unpack12(rowp, lane, k);
        float mx = -1e30f;
#pragma unroll
        for (int j = 0; j < 12; ++j) {
            p[j] = gv[j] * k[j];
            t[j] = p[j] * bt[j] * SM_SCALE;
            mx = fmaxf(mx, t[j]);
        }
#pragma unroll
        for (int s = 32; s > 0; s >>= 1) mx = fmaxf(mx, __shfl_xor(mx, s));
        float sum = 0.f, e[12];
#pragma unroll
        for (int j = 0; j < 12; ++j) { e[j] = __expf(t[j] - mx); sum += e[j]; }
#pragma unroll
        for (int s = 32; s > 0; s >>= 1) sum += __shfl_xor(sum, s);
        float inv = 1.f / sum;
#pragma unroll
        for (int j = 0; j < 12; ++j) acc[j] += p[j] * e[j] * inv;
    }
    float* g = gk + b * KD;
#pragma unroll
    for (int j = 0; j < 8; ++j) atomicAdd(&g[lane * 8 + j], acc[j]);
#pragma unroll
    for (int j = 0; j < 4; ++j) atomicAdd(&g[512 + lane * 4 + j], acc[8 + j]);
}

// WrS[b][e][d] = bf16(WrT[e][d] * gk[b][d]); 8 elems/thread, grid 2304
__global__ __launch_bounds__(256) void scale_wr(const unsigned short* __restrict__ WrT,
                                                const float* __restrict__ gk,
                                                unsigned short* __restrict__ WrS) {
    int i = blockIdx.x * 256 + threadIdx.x;  // < 8*73728
    const int per = (KD * KD) / 8;           // 73728
    int b = i / per, g = i % per;
    int d = (g % (KD / 8)) * 8;
    uint4 w = *((const uint4*)WrT + g);
    const float* gkb = gk + b * KD + d;
    float4 s0 = *(const float4*)gkb;
    float4 s1 = *((const float4*)gkb + 1);
    union { unsigned short s[8]; uint4 u; } o;
    o.s[0] = f2bf(__uint_as_float(w.x << 16) * s0.x);
    o.s[1] = f2bf(__uint_as_float(w.x & 0xffff0000u) * s0.y);
    o.s[2] = f2bf(__uint_as_float(w.y << 16) * s0.z);
    o.s[3] = f2bf(__uint_as_float(w.y & 0xffff0000u) * s0.w);
    o.s[4] = f2bf(__uint_as_float(w.z << 16) * s1.x);
    o.s[5] = f2bf(__uint_as_float(w.z & 0xffff0000u) * s1.y);
    o.s[6] = f2bf(__uint_as_float(w.w << 16) * s1.z);
    o.s[7] = f2bf(__uint_as_float(w.w & 0xffff0000u) * s1.w);
    ((uint4*)WrS)[i] = o.u;
}

// ---------- launch ----------

extern "C" void kernel_launch(void* const* d_in, const int* in_sizes, int n_in,
                              void* d_out, int out_size, void* d_ws, size_t ws_size,
                              hipStream_t stream) {
    const float* x     = (const float*)d_in[0];
    const float* Wq    = (const float*)d_in[1];
    const float* Wk    = (const float*)d_in[2];
    const float* Wv    = (const float*)d_in[3];
    const float* Wr    = (const float*)d_in[4];
    const float* alpha = (const float*)d_in[5];
    const float* beta  = (const float*)d_in[6];
    float* out = (float*)d_out;
    char* ws = (char*)d_ws;

    // workspace layout (bytes), total ~124.3 MB
    unsigned short* xb  = (unsigned short*)(ws);              // 50,331,648
    unsigned short* qk  = (unsigned short*)(ws + 50331648);   // 50,331,648 (q then reused for k)
    unsigned short* WqT = (unsigned short*)(ws + 100663296);  // 1,179,648
    unsigned short* WkT = (unsigned short*)(ws + 101842944);  // 1,179,648
    unsigned short* WrT = (unsigned short*)(ws + 103022592);  // 1,179,648
    unsigned short* Wvb = (unsigned short*)(ws + 104202240);  // 1,179,648
    unsigned short* WrS = (unsigned short*)(ws + 105381888);  // 9,437,184
    unsigned short* W3T = (unsigned short*)(ws + 114819072);  // 9,437,184
    float* gq = (float*)(ws + 124256256);                     // 24,576
    float* gk = (float*)(ws + 124280832);                     // 24,576

    hipMemsetAsync(gq, 0, 49152, stream);  // zero gq+gk (ws is poisoned 0xAA each call)

    cvt_f32_bf16x8<<<12288, 256, 0, stream>>>(x, xb, (ROWS * KD) / 8);
    transpose_to_bf16<<<dim3(24, 24), 256, 0, stream>>>(Wq, WqT);
    transpose_to_bf16<<<dim3(24, 24), 256, 0, stream>>>(Wk, WkT);
    transpose_to_bf16<<<dim3(24, 24), 256, 0, stream>>>(Wr, WrT);
    cvt_f32_bf16x8<<<288, 256, 0, stream>>>(Wv, Wvb, (KD * KD) / 8);

    gemm_bf16<<<dim3(6, 256), 256, 0, stream>>>(xb, WqT, qk);      // q
    reduce_gq<<<dim3(32, NBATCH), 256, 0, stream>>>(qk, alpha, gq);
    gemm_bf16<<<dim3(6, 256), 256, 0, stream>>>(xb, WkT, qk);      // k (reuses buffer)
    reduce_gk<<<dim3(32, NBATCH), 256, 0, stream>>>(qk, gq, beta, gk);

    scale_wr<<<2304, 256, 0, stream>>>(WrT, gk, WrS);
    gemm_w3<<<dim3(6, 6, NBATCH), 256, 0, stream>>>(WrS, Wvb, Wq, W3T);
    gemm_out_f32<<<dim3(6, 256), 256, 0, stream>>>(xb, W3T, out);
}